// Round 1
// baseline (151.240 us; speedup 1.0000x reference)
//
#include <hip/hip_runtime.h>
#include <hip/hip_bf16.h>

using short8  = __attribute__((ext_vector_type(8))) short;
using floatx4 = __attribute__((ext_vector_type(4))) float;

#define GPTR(p) ((const __attribute__((address_space(1))) void*)(p))
#define LPTR(p) ((__attribute__((address_space(3))) void*)(p))

// ---------------------------------------------------------------------------
// pack_x: unfold x [16,1,1024,1024] fp32 -> patches [16384 x 1024] bf16
// patch row p = b*1024 + nh*32 + nw ; col k = kh*32 + kw
// one thread = 8 consecutive k (one 16B bf16 chunk). 2^21 chunks total.
// writes: wave-contiguous 1 KiB; reads: 128 B segments (full cache lines).
// ---------------------------------------------------------------------------
__global__ __launch_bounds__(256) void pack_x_kernel(const float* __restrict__ x,
                                                     __hip_bfloat16* __restrict__ patches) {
    const int c   = blockIdx.x * 256 + threadIdx.x;   // 0 .. 2^21-1
    const int kw8 = c & 3;
    const int kh  = (c >> 2) & 31;
    const int p   = (c >> 7) & 1023;
    const int b   = c >> 17;
    const int nh = p >> 5, nw = p & 31;
    const float* src = x + ((size_t)b << 20) + (size_t)(nh * 32 + kh) * 1024 + nw * 32 + kw8 * 8;
    floatx4 v0 = *(const floatx4*)(src);
    floatx4 v1 = *(const floatx4*)(src + 4);
    union { short8 s; __hip_bfloat16 h[8]; } u;
#pragma unroll
    for (int i = 0; i < 4; ++i) {
        u.h[i]     = __float2bfloat16(v0[i]);
        u.h[4 + i] = __float2bfloat16(v1[i]);
    }
    *(short8*)(patches + (size_t)c * 8) = u.s;
}

// ---------------------------------------------------------------------------
// pack_w: convert both weight matrices fp32 -> bf16 (layouts already B^T form)
// w_sample [256 x 1024] (N=SP, K=BS*BS), w_init [1024 x 256] (N=BS*BS, K=SP)
// 262144 elems each -> 32768 chunks each, 65536 threads.
// ---------------------------------------------------------------------------
__global__ __launch_bounds__(256) void pack_w_kernel(const float* __restrict__ w_sample,
                                                     const float* __restrict__ w_init,
                                                     __hip_bfloat16* __restrict__ wsb,
                                                     __hip_bfloat16* __restrict__ wib) {
    const int c = blockIdx.x * 256 + threadIdx.x;     // 0 .. 65535
    const float* src;
    __hip_bfloat16* dst;
    if (c < 32768) { src = w_sample + (size_t)c * 8;           dst = wsb + (size_t)c * 8; }
    else           { src = w_init   + (size_t)(c - 32768) * 8; dst = wib + (size_t)(c - 32768) * 8; }
    floatx4 v0 = *(const floatx4*)(src);
    floatx4 v1 = *(const floatx4*)(src + 4);
    union { short8 s; __hip_bfloat16 h[8]; } u;
#pragma unroll
    for (int i = 0; i < 4; ++i) {
        u.h[i]     = __float2bfloat16(v0[i]);
        u.h[4 + i] = __float2bfloat16(v1[i]);
    }
    *(short8*)(dst) = u.s;
}

// ---------------------------------------------------------------------------
// gemm_bt: C[M,N] = A[M,K] * Bt[N,K]^T, bf16 in, fp32 accum.
// m97-style: 256 threads = 4 waves in 2x2; BK=64; global_load_lds width 16;
// MFMA 16x16x32 bf16; As/Bs [rows][64] unpadded (global_load_lds dest must be
// wave-uniform base + lane*16).
// EPI=0: store C as bf16 row-major (ldc = N).
// EPI=1: fold-store fp32 into y: row=p -> (b,nh,nw), col=k' -> (kh,kw).
// Verified layouts: A/Bt frag row = lane&15, k = quad*8+j (ds_read_b128);
// C/D: col = lane&15, row = quad*4 + reg.
// ---------------------------------------------------------------------------
template <int BM, int BN, int KDIM, int EPI>
__global__ __launch_bounds__(256) void gemm_bt(const __hip_bfloat16* __restrict__ A,
                                               const __hip_bfloat16* __restrict__ Bt,
                                               __hip_bfloat16* __restrict__ Cbf,
                                               float* __restrict__ Y,
                                               int M, int N) {
    constexpr int BK = 64;
    constexpr int WM = BM / 2, WN = BN / 2;     // 2x2 wave grid
    constexpr int MI = WM / 16, NI = WN / 16;
    constexpr int AISS = BM * 8 / 256;          // 16B-chunk issues per thread
    constexpr int BISS = BN * 8 / 256;
    (void)M;

    __shared__ __hip_bfloat16 As[BM * BK];
    __shared__ __hip_bfloat16 Bs[BN * BK];

    const int tid  = threadIdx.x;
    const int wave = tid >> 6, lane = tid & 63;
    const int quad = lane >> 4, l16 = lane & 15;
    const int wm = wave & 1, wn = wave >> 1;

    const int nbN = N / BN;
    const int bm = blockIdx.x / nbN, bn = blockIdx.x % nbN;
    const long m0 = (long)bm * BM, n0 = (long)bn * BN;

    const __hip_bfloat16* Ab = A + m0 * KDIM;
    const __hip_bfloat16* Bb = Bt + n0 * KDIM;

    floatx4 acc[MI][NI];
#pragma unroll
    for (int i = 0; i < MI; ++i)
#pragma unroll
        for (int j = 0; j < NI; ++j)
            acc[i][j] = {0.0f, 0.0f, 0.0f, 0.0f};

    for (int k0 = 0; k0 < KDIM; k0 += BK) {
#pragma unroll
        for (int i = 0; i < AISS; ++i) {
            const int c = i * 256 + tid;           // chunk id: row = c>>3, kpart = (c&7)*8
            __builtin_amdgcn_global_load_lds(GPTR(Ab + (long)(c >> 3) * KDIM + k0 + (c & 7) * 8),
                                             LPTR(&As[c * 8]), 16, 0, 0);
        }
#pragma unroll
        for (int i = 0; i < BISS; ++i) {
            const int c = i * 256 + tid;
            __builtin_amdgcn_global_load_lds(GPTR(Bb + (long)(c >> 3) * KDIM + k0 + (c & 7) * 8),
                                             LPTR(&Bs[c * 8]), 16, 0, 0);
        }
        __syncthreads();                            // drains vmcnt before barrier

#pragma unroll
        for (int kk = 0; kk < 2; ++kk) {
            short8 af[MI], bfr[NI];
#pragma unroll
            for (int i = 0; i < MI; ++i)
                af[i] = *(const short8*)&As[(wm * WM + i * 16 + l16) * BK + kk * 32 + quad * 8];
#pragma unroll
            for (int j = 0; j < NI; ++j)
                bfr[j] = *(const short8*)&Bs[(wn * WN + j * 16 + l16) * BK + kk * 32 + quad * 8];
#pragma unroll
            for (int i = 0; i < MI; ++i)
#pragma unroll
                for (int j = 0; j < NI; ++j)
                    acc[i][j] = __builtin_amdgcn_mfma_f32_16x16x32_bf16(af[i], bfr[j], acc[i][j], 0, 0, 0);
        }
        __syncthreads();
    }

    if constexpr (EPI == 0) {
#pragma unroll
        for (int i = 0; i < MI; ++i)
#pragma unroll
            for (int r = 0; r < 4; ++r) {
                const long row = m0 + wm * WM + i * 16 + quad * 4 + r;
#pragma unroll
                for (int j = 0; j < NI; ++j) {
                    const long col = n0 + wn * WN + j * 16 + l16;
                    Cbf[row * N + col] = __float2bfloat16(acc[i][j][r]);
                }
            }
    } else {
#pragma unroll
        for (int i = 0; i < MI; ++i)
#pragma unroll
            for (int r = 0; r < 4; ++r) {
                const int row = (int)m0 + wm * WM + i * 16 + quad * 4 + r;   // global patch idx
                const int b  = row >> 10, pl = row & 1023;
                const int nh = pl >> 5,  nw = pl & 31;
                const size_t base = ((size_t)b << 20) + (size_t)nh * 32768 + (size_t)nw * 32;
#pragma unroll
                for (int j = 0; j < NI; ++j) {
                    const int col = (int)n0 + wn * WN + j * 16 + l16;        // k' = kh*32+kw
                    const int kh = col >> 5, kw = col & 31;
                    Y[base + (size_t)kh * 1024 + kw] = acc[i][j][r];
                }
            }
    }
}

// ---------------------------------------------------------------------------
// Workspace layout (total ~42.9 MB):
//   patches bf16 [16384*1024]  @ 0          (33554432 B)
//   meas    bf16 [16384*256]   @ 33554432   ( 8388608 B)
//   wsb     bf16 [256*1024]    @ 41943040   (  524288 B)
//   wib     bf16 [1024*256]    @ 42467328   (  524288 B)
// ---------------------------------------------------------------------------
extern "C" void kernel_launch(void* const* d_in, const int* in_sizes, int n_in,
                              void* d_out, int out_size, void* d_ws, size_t ws_size,
                              hipStream_t stream) {
    const float* x        = (const float*)d_in[0];
    const float* w_sample = (const float*)d_in[1];
    const float* w_init   = (const float*)d_in[2];
    float* y = (float*)d_out;
    char* ws = (char*)d_ws;

    __hip_bfloat16* patches = (__hip_bfloat16*)(ws);
    __hip_bfloat16* meas    = (__hip_bfloat16*)(ws + (size_t)33554432);
    __hip_bfloat16* wsb     = (__hip_bfloat16*)(ws + (size_t)41943040);
    __hip_bfloat16* wib     = (__hip_bfloat16*)(ws + (size_t)42467328);

    pack_x_kernel<<<8192, 256, 0, stream>>>(x, patches);
    pack_w_kernel<<<256, 256, 0, stream>>>(w_sample, w_init, wsb, wib);
    // GEMM1: meas[16384,256] = patches[16384,1024] @ w_sample[256,1024]^T
    gemm_bt<64, 128, 1024, 0><<<512, 256, 0, stream>>>(patches, wsb, meas, nullptr, 16384, 256);
    // GEMM2: y(fold) <- meas[16384,256] @ w_init[1024,256]^T
    gemm_bt<128, 128, 256, 1><<<1024, 256, 0, stream>>>(meas, wib, nullptr, y, 16384, 1024);
}